// Round 3
// baseline (576.772 us; speedup 1.0000x reference)
//
#include <hip/hip_runtime.h>
#include <hip/hip_cooperative_groups.h>
#include <math.h>

namespace cg = cooperative_groups;

#define B    32
#define C    512
#define R    32      // C / RATIO
#define HW   4096    // 64*64
#define HALF 256     // C/2
#define TPB  256

typedef float v4f __attribute__((ext_vector_type(4)));

// ================= Fused cooperative kernel =================
// Phase A (means) -> grid.sync -> Phase B (MLP+topk) -> grid.sync -> Phase C (gather).
// All phases grid-stride so ANY co-resident grid size is correct.
__global__ __launch_bounds__(TPB, 4) void se_fused_kernel(const float* __restrict__ x,
                                                          const float* __restrict__ w1,
                                                          const float* __restrict__ w2,
                                                          float* __restrict__ means,
                                                          int* __restrict__ idx,
                                                          float* __restrict__ gate,
                                                          float* __restrict__ out) {
    cg::grid_group grid = cg::this_grid();
    const int t      = threadIdx.x;
    const int lane   = t & 63;
    const int wid    = t >> 6;
    const int nwaves = gridDim.x * 4;
    const int gw     = blockIdx.x * 4 + wid;

    // ---------- Phase A: per-(b,c) mean over H*W (one wave per row) ----------
    for (int row = gw; row < B * C; row += nwaves) {
        const v4f* p = (const v4f*)(x + (size_t)row * HW);
        v4f v[16];
#pragma unroll
        for (int i = 0; i < 16; ++i) v[i] = p[lane + 64 * i];
        float s = 0.f;
#pragma unroll
        for (int i = 0; i < 16; ++i) s += (v[i].x + v[i].y) + (v[i].z + v[i].w);
#pragma unroll
        for (int off = 32; off > 0; off >>= 1) s += __shfl_down(s, off, 64);
        if (lane == 0) means[row] = s * (1.0f / HW);
    }

    grid.sync();   // means visible device-wide

    // ---------- Phase B: MLP gates + stable top-256 (one block per batch) ----------
    __shared__ float sm[C];
    __shared__ float ps[R][9];     // 8 segments + pad
    __shared__ float sy1[R];
    __shared__ float sy2[C];
    for (int b = blockIdx.x; b < B; b += gridDim.x) {
        sm[t]       = means[b * C + t];
        sm[t + 256] = means[b * C + t + 256];
        __syncthreads();

        // y1[r] = relu( sum_c mean[c] * w1[r][c] ): 8 segments of 64 channels
        {
            const int r   = t & 31;
            const int seg = t >> 5;     // 0..7
            const int c0  = seg * 64;
            float acc = 0.f;
#pragma unroll
            for (int i = 0; i < 64; ++i) acc += sm[c0 + i] * w1[r * C + c0 + i];
            ps[r][seg] = acc;
        }
        __syncthreads();
        if (t < R) {
            float acc = 0.f;
#pragma unroll
            for (int s = 0; s < 8; ++s) acc += ps[t][s];
            sy1[t] = fmaxf(acc, 0.f);
        }
        __syncthreads();

        // y2[c] = sigmoid( sum_r y1[r] * w2[c][r] ), 2 channels/thread
#pragma unroll
        for (int h = 0; h < 2; ++h) {
            const int c = t + h * 256;
            float acc = 0.f;
#pragma unroll
            for (int r = 0; r < R; ++r) acc += sy1[r] * w2[c * R + r];
            sy2[c] = 1.0f / (1.0f + expf(-acc));
        }
        __syncthreads();

        // stable descending rank == jax.lax.top_k (ties -> lower index first)
#pragma unroll
        for (int h = 0; h < 2; ++h) {
            const int c = t + h * 256;
            const float v = sy2[c];
            const v4f* sv = (const v4f*)sy2;
            int rank = 0;
#pragma unroll 4
            for (int j4 = 0; j4 < C / 4; ++j4) {
                v4f u = sv[j4];
                const int j = j4 * 4;
                rank += (u.x > v) || (u.x == v && (j + 0) < c);
                rank += (u.y > v) || (u.y == v && (j + 1) < c);
                rank += (u.z > v) || (u.z == v && (j + 2) < c);
                rank += (u.w > v) || (u.w == v && (j + 3) < c);
            }
            if (rank < HALF) {
                idx[b * HALF + rank]  = c;
                gate[b * HALF + rank] = v;
            }
        }
        __syncthreads();   // WAR guard if a block handles multiple b
    }

    grid.sync();   // idx/gate visible device-wide

    // ---------- Phase C: gather + scale (one wave per output row) ----------
    for (int bk = gw; bk < B * HALF; bk += nwaves) {
        const int b   = bk >> 8;                 // / HALF
        const int ch  = idx[bk];
        const float g = gate[bk];
        const v4f* src = (const v4f*)(x + ((size_t)b * C + ch) * HW);
        v4f* dst = (v4f*)(out + (size_t)bk * HW);
#pragma unroll
        for (int i = 0; i < 16; ++i) {
            v4f v = src[lane + 64 * i];
            v *= g;
            __builtin_nontemporal_store(v, &dst[lane + 64 * i]);
        }
    }
}

// ================= Fallback path: proven 3-kernel version (R1, 429.8 us) =================
__global__ __launch_bounds__(256) void se_mean_kernel(const float* __restrict__ x,
                                                      float* __restrict__ means) {
    const int t    = threadIdx.x;
    const int lane = t & 63;
    const int wid  = t >> 6;
    const int row0 = (blockIdx.x * 4 + wid) * 2;
    const v4f* p0 = (const v4f*)(x + (size_t)row0 * HW);
    const v4f* p1 = (const v4f*)(x + (size_t)row0 * HW + HW);

    v4f va[16], vb[16];
#pragma unroll
    for (int i = 0; i < 16; ++i) va[i] = p0[lane + 64 * i];
#pragma unroll
    for (int i = 0; i < 16; ++i) vb[i] = p1[lane + 64 * i];

    float s0 = 0.f, s1 = 0.f;
#pragma unroll
    for (int i = 0; i < 16; ++i) s0 += (va[i].x + va[i].y) + (va[i].z + va[i].w);
#pragma unroll
    for (int i = 0; i < 16; ++i) s1 += (vb[i].x + vb[i].y) + (vb[i].z + vb[i].w);

#pragma unroll
    for (int off = 32; off > 0; off >>= 1) {
        s0 += __shfl_down(s0, off, 64);
        s1 += __shfl_down(s1, off, 64);
    }
    if (lane == 0) {
        means[row0]     = s0 * (1.0f / HW);
        means[row0 + 1] = s1 * (1.0f / HW);
    }
}

__global__ __launch_bounds__(512) void se_gate_topk_kernel(const float* __restrict__ means,
                                                           const float* __restrict__ w1,
                                                           const float* __restrict__ w2,
                                                           int* __restrict__ idx_out,
                                                           float* __restrict__ gate_out) {
    const int b = blockIdx.x;
    const int t = threadIdx.x;
    __shared__ float sm[C];
    __shared__ float ps[R][17];
    __shared__ float sy1[R];
    __shared__ float sy2[C];

    sm[t] = means[b * C + t];
    __syncthreads();
    {
        const int r   = t & 31;
        const int seg = t >> 5;
        const int c0  = seg * 32;
        float acc = 0.f;
#pragma unroll
        for (int i = 0; i < 32; ++i) acc += sm[c0 + i] * w1[r * C + c0 + i];
        ps[r][seg] = acc;
    }
    __syncthreads();
    if (t < R) {
        float acc = 0.f;
#pragma unroll
        for (int s = 0; s < 16; ++s) acc += ps[t][s];
        sy1[t] = fmaxf(acc, 0.f);
    }
    __syncthreads();
    {
        float acc = 0.f;
#pragma unroll
        for (int r = 0; r < R; ++r) acc += sy1[r] * w2[t * R + r];
        sy2[t] = 1.0f / (1.0f + expf(-acc));
    }
    __syncthreads();

    const float v = sy2[t];
    const v4f* sv = (const v4f*)sy2;
    int rank = 0;
#pragma unroll 4
    for (int j4 = 0; j4 < C / 4; ++j4) {
        v4f u = sv[j4];
        const int j = j4 * 4;
        rank += (u.x > v) || (u.x == v && (j + 0) < t);
        rank += (u.y > v) || (u.y == v && (j + 1) < t);
        rank += (u.z > v) || (u.z == v && (j + 2) < t);
        rank += (u.w > v) || (u.w == v && (j + 3) < t);
    }
    if (rank < HALF) {
        idx_out[b * HALF + rank]  = t;
        gate_out[b * HALF + rank] = v;
    }
}

__global__ __launch_bounds__(256) void se_gather_scale_kernel(const float* __restrict__ x,
                                                              const int* __restrict__ idx,
                                                              const float* __restrict__ gate,
                                                              float* __restrict__ out) {
    const int t    = threadIdx.x;
    const int lane = t & 63;
    const int wid  = t >> 6;
    const int bk   = blockIdx.x * 4 + wid;
    const int b    = bk >> 8;
    const int ch   = idx[bk];
    const float g  = gate[bk];
    const v4f* src = (const v4f*)(x + ((size_t)b * C + ch) * HW);
    v4f* dst = (v4f*)(out + (size_t)bk * HW);

#pragma unroll
    for (int i = 0; i < 16; ++i) {
        v4f v = src[lane + 64 * i];
        v *= g;
        __builtin_nontemporal_store(v, &dst[lane + 64 * i]);
    }
}

// ================= Host =================
extern "C" void kernel_launch(void* const* d_in, const int* in_sizes, int n_in,
                              void* d_out, int out_size, void* d_ws, size_t ws_size,
                              hipStream_t stream) {
    const float* x  = (const float*)d_in[0];
    const float* w1 = (const float*)d_in[1];
    const float* w2 = (const float*)d_in[2];
    float* out = (float*)d_out;

    // workspace layout: means (B*C f32) | idx (B*HALF i32) | gate (B*HALF f32)
    float* means = (float*)d_ws;
    int*   idx   = (int*)((char*)d_ws + B * C * 4);
    float* gate  = (float*)((char*)d_ws + B * C * 4 + B * HALF * 4);

    // Size the cooperative grid from the actual occupancy (cached).
    static int coop_grid = -2;   // -2 = uninitialized, -1 = cooperative path disabled
    if (coop_grid == -2) {
        int maxB = 0, cus = 0, dev = 0;
        (void)hipGetDevice(&dev);
        if (hipOccupancyMaxActiveBlocksPerMultiprocessor(&maxB, (const void*)se_fused_kernel,
                                                         TPB, 0) != hipSuccess) maxB = 0;
        if (hipDeviceGetAttribute(&cus, hipDeviceAttributeMultiprocessorCount, dev) != hipSuccess) cus = 0;
        long total = (long)maxB * (long)cus;
        coop_grid = (total >= 64) ? (int)(total > 2048 ? 2048 : total) : -1;
    }

    bool done = false;
    if (coop_grid > 0) {
        void* args[] = {(void*)&x, (void*)&w1, (void*)&w2,
                        (void*)&means, (void*)&idx, (void*)&gate, (void*)&out};
        if (hipLaunchCooperativeKernel((const void*)se_fused_kernel, dim3(coop_grid), dim3(TPB),
                                       args, 0, stream) == hipSuccess) {
            done = true;
        } else {
            coop_grid = -1;   // don't retry on later calls
        }
    }
    if (!done) {
        se_mean_kernel<<<B * C / 8, 256, 0, stream>>>(x, means);
        se_gate_topk_kernel<<<B, 512, 0, stream>>>(means, w1, w2, idx, gate);
        se_gather_scale_kernel<<<B * HALF / 4, 256, 0, stream>>>(x, idx, gate, out);
    }
}